// Round 7
// baseline (168.307 us; speedup 1.0000x reference)
//
#include <hip/hip_runtime.h>
#include <math.h>

#define T_MAX 11  // MAX_TURNS from the reference

typedef float f4 __attribute__((ext_vector_type(4)));  // nontemporal-compatible

// per-segment param block layout in workspace (16 floats, 64 B):
//   [0..11]  weights w_k (padded with 0)
//   [12]     o (offset) as int bits
//   [13]     n as int bits
//   [14,15]  unused

// ---------------------------------------------------------------------------
// Kernel 1: probs + per-segment params + mtl segment-sum. Grid = S blocks.
// ---------------------------------------------------------------------------
__global__ __launch_bounds__(256) void k_probs(
    const float*  __restrict__ hist,       // [rows, hidden]
    const float4* __restrict__ mtl4,       // [rows, hidden/4]
    const float*  __restrict__ W,          // [hidden]
    const float*  __restrict__ b,          // [1]
    const int*    __restrict__ slice_mask, // [>=S]
    int S, int rows, int hidden,
    float*  __restrict__ probs_out,        // [S, T_MAX]
    float4* __restrict__ out_mtl,          // [S, hidden/4]
    float*  __restrict__ params)           // [S, 16]
{
    __shared__ float s_exp[64];
    __shared__ float s_wk[64];
    __shared__ int   s_off, s_n;

    const int sidx = blockIdx.x;
    const int tid  = threadIdx.x;
    const int lane = tid & 63;
    const int wave = tid >> 6;

    if (tid == 0) {
        int acc = 0, n = 0;
        for (int i = 0; i < S; ++i) {
            const int v = slice_mask[i];
            if (i < sidx) acc += v;
            if (i == sidx) n = v;
        }
        s_off = acc; s_n = n;
    }
    __syncthreads();

    const int o  = s_off;
    const int n  = s_n;
    const int h4 = hidden >> 2;
    const float4* W4 = (const float4*)W;

    for (int k = wave; k < n; k += 4) {
        const int idx = min(o + k, rows - 1);
        const float4* hrow = (const float4*)(hist + (size_t)idx * hidden);
        float acc = 0.0f;
        for (int j = lane; j < h4; j += 64) {
            const float4 hv = hrow[j];
            const float4 wv = W4[j];
            acc += hv.x*wv.x + hv.y*wv.y + hv.z*wv.z + hv.w*wv.w;
        }
        #pragma unroll
        for (int d = 32; d > 0; d >>= 1)
            acc += __shfl_down(acc, d);
        if (lane == 0) s_exp[k] = expf(acc + b[0]);
    }
    __syncthreads();

    if (tid == 0) {
        float sum = 0.0f;
        for (int k = 0; k < n; ++k) sum += s_exp[k];
        const float inv = 1.0f / sum;
        float* pp = params + sidx * 16;
        for (int k = 0; k < 12; ++k) {
            const float wk = (k < n) ? s_exp[k] * inv : 0.0f;
            s_wk[k] = wk;
            pp[k] = wk;
        }
        ((int*)pp)[12] = o;
        ((int*)pp)[13] = n;
    }
    __syncthreads();

    if (tid < T_MAX) {
        const int pad = T_MAX - n;
        probs_out[sidx * T_MAX + tid] = (tid >= pad && tid - pad < n)
                                        ? s_wk[tid - pad] : 0.0f;
    }

    // mtl segment-sum for this segment (hidden/4 = 192 float4 columns)
    for (int i = tid; i < h4; i += 256) {
        float4 acc = {0.f, 0.f, 0.f, 0.f};
        for (int k = 0; k < n; ++k) {
            const float wk = s_wk[k];
            const int r = min(o + k, rows - 1);
            const float4 v = mtl4[(size_t)r * h4 + i];
            acc.x += wk * v.x; acc.y += wk * v.y;
            acc.z += wk * v.z; acc.w += wk * v.w;
        }
        out_mtl[(size_t)sidx * h4 + i] = acc;
    }
}

// ---------------------------------------------------------------------------
// Kernel 2: pure bert weighted segment-sum. No LDS, no barriers.
// Loads are PLAIN (bert is L2/L3-warm from the harness restore copy — keep
// the cache hits); stores stay non-temporal (output never re-read).
// Grid tiles the column space exactly -> branch-free fast path, 16
// independent loads in flight before any FMA.
// ---------------------------------------------------------------------------
__global__ __launch_bounds__(256) void k_segsum(
    const f4* __restrict__ bert,
    const float* __restrict__ params,      // [S,16]
    int nchunks, int bert_cols4, int rows,
    f4* __restrict__ out_bert)
{
    const int sidx  = blockIdx.x / nchunks;
    const int chunk = blockIdx.x - sidx * nchunks;
    const int tid   = threadIdx.x;

    const float* pp = params + sidx * 16;
    const f4 wv = *(const f4*)pp;              // w0..w3
    const int o = ((const int*)pp)[12];
    const int n = ((const int*)pp)[13];

    const int base = chunk * 1024 + tid;
    f4* outp = out_bert + (size_t)sidx * bert_cols4;

    if (n == 4) {
        const f4* r0 = bert + (size_t)min(o + 0, rows - 1) * bert_cols4;
        const f4* r1 = bert + (size_t)min(o + 1, rows - 1) * bert_cols4;
        const f4* r2 = bert + (size_t)min(o + 2, rows - 1) * bert_cols4;
        const f4* r3 = bert + (size_t)min(o + 3, rows - 1) * bert_cols4;

        f4 v[4][4];
        #pragma unroll
        for (int j = 0; j < 4; ++j) {
            const int i = base + j * 256;
            v[j][0] = r0[i];
            v[j][1] = r1[i];
            v[j][2] = r2[i];
            v[j][3] = r3[i];
        }
        #pragma unroll
        for (int j = 0; j < 4; ++j) {
            const int i = base + j * 256;
            f4 acc = wv.x * v[j][0] + wv.y * v[j][1]
                   + wv.z * v[j][2] + wv.w * v[j][3];
            __builtin_nontemporal_store(acc, &outp[i]);
        }
    } else if (n == 1) {
        const f4* r0 = bert + (size_t)min(o, rows - 1) * bert_cols4;
        #pragma unroll
        for (int j = 0; j < 4; ++j) {
            const int i = base + j * 256;
            const f4 acc = wv.x * r0[i];
            __builtin_nontemporal_store(acc, &outp[i]);
        }
    } else {
        #pragma unroll
        for (int j = 0; j < 4; ++j) {
            const int i = base + j * 256;
            f4 acc = {0.f, 0.f, 0.f, 0.f};
            for (int k = 0; k < n; ++k) {
                const float wk = pp[min(k, 11)];
                const int r = min(o + k, rows - 1);
                acc += wk * bert[(size_t)r * bert_cols4 + i];
            }
            __builtin_nontemporal_store(acc, &outp[i]);
        }
    }
}

extern "C" void kernel_launch(void* const* d_in, const int* in_sizes, int n_in,
                              void* d_out, int out_size, void* d_ws, size_t ws_size,
                              hipStream_t stream) {
    const float* bert = (const float*)d_in[0];
    const float* hist = (const float*)d_in[1];
    const float* mtl  = (const float*)d_in[2];
    const float* W    = (const float*)d_in[3];
    const float* b    = (const float*)d_in[4];
    const int* slice_mask = (const int*)d_in[5];

    const int hidden = in_sizes[3];                       // 768
    const int rows   = in_sizes[1] / hidden;              // 64
    const int seq    = in_sizes[0] / (rows * hidden);     // 512
    const int S = out_size / (seq * hidden + hidden + T_MAX);   // 16

    float* out       = (float*)d_out;
    float* out_bert  = out;
    float* out_mtl   = out_bert + (size_t)S * seq * hidden;
    float* out_probs = out_mtl  + (size_t)S * hidden;

    float* params = (float*)d_ws;   // [S,16] floats

    k_probs<<<S, 256, 0, stream>>>(hist, (const float4*)mtl, W, b, slice_mask,
                                   S, rows, hidden,
                                   out_probs, (float4*)out_mtl, params);

    const int bert_cols4 = seq * hidden / 4;              // 98304 (96*1024)
    const int chunk_f4   = 1024;                          // 4 f4 per thread
    const int nchunks    = (bert_cols4 + chunk_f4 - 1) / chunk_f4;  // 96
    const int grid       = S * nchunks;                   // 1536

    k_segsum<<<grid, 256, 0, stream>>>((const f4*)bert, params,
                                       nchunks, bert_cols4, rows,
                                       (f4*)out_bert);
}

// Round 8
// 156.605 us; speedup vs baseline: 1.0747x; 1.0747x over previous
//
#include <hip/hip_runtime.h>
#include <math.h>

#define T_MAX 11  // MAX_TURNS from the reference

typedef float f4 __attribute__((ext_vector_type(4)));  // nontemporal-compatible

// ---------------------------------------------------------------------------
// Single fused kernel. Grid = S * nchunks blocks of 256 (4 waves).
// Prologue (every block, ~2 us latency, hidden by other blocks' streaming):
//   - all threads read the 16 slice_mask values (uniform broadcast loads),
//     compute (o, n) in registers — no barrier;
//   - wave w computes the 768-dot for row o+w (3 f4 loads/lane + 6-shuffle
//     reduce + expf) -> s_e[w]; slots >= n zeroed; ONE __syncthreads();
//   - every thread forms inv = 1/sum(s_e) and its weights from LDS.
// Main body = R6's branch-free n==4 fast path: 16 independent NT loads in
// flight before any FMA, NT stores (write-once output).
// chunk==0 blocks also write probs[sidx] and the mtl output row.
// ---------------------------------------------------------------------------
__global__ __launch_bounds__(256) void k_fused(
    const f4*    __restrict__ bert,        // [rows, bert_cols4]
    const float* __restrict__ hist,        // [rows, hidden]
    const f4*    __restrict__ mtl4,        // [rows, hidden/4]
    const float* __restrict__ W,           // [hidden]
    const float* __restrict__ b,           // [1]
    const int*   __restrict__ slice_mask,  // [>=S]
    int S, int rows, int hidden,
    int nchunks, int bert_cols4,
    f4*    __restrict__ out_bert,          // [S, bert_cols4]
    f4*    __restrict__ out_mtl,           // [S, hidden/4]
    float* __restrict__ probs_out)         // [S, T_MAX]
{
    __shared__ float s_e[T_MAX + 1];

    const int sidx  = blockIdx.x / nchunks;
    const int chunk = blockIdx.x - sidx * nchunks;
    const int tid   = threadIdx.x;
    const int lane  = tid & 63;
    const int wave  = tid >> 6;

    // ---- (o, n) in registers: uniform broadcast loads, no barrier ----
    int o = 0, n = 0;
    #pragma unroll
    for (int i = 0; i < 16; ++i) {          // S == 16 here; guarded below
        const int v = (i < S) ? slice_mask[i] : 0;
        if (i < sidx)  o += v;
        if (i == sidx) n = v;
    }

    // ---- zero exp slots >= n (disjoint from wave writes below) ----
    if (tid < T_MAX && tid >= n) s_e[tid] = 0.0f;

    // ---- one wave per valid row dot-product ----
    const int h4 = hidden >> 2;             // 192
    const f4* W4 = (const f4*)W;
    for (int k = wave; k < n; k += 4) {
        const int idx = min(o + k, rows - 1);
        const f4* hrow = (const f4*)(hist + (size_t)idx * hidden);
        float acc = 0.0f;
        for (int j = lane; j < h4; j += 64) {
            const f4 hv = hrow[j];
            const f4 wv = W4[j];
            acc += hv.x * wv.x + hv.y * wv.y + hv.z * wv.z + hv.w * wv.w;
        }
        #pragma unroll
        for (int d = 32; d > 0; d >>= 1)
            acc += __shfl_down(acc, d);
        if (lane == 0) s_e[k] = expf(acc + b[0]);
    }
    __syncthreads();

    // ---- every thread: softmax denominator + weights ----
    float sum = 0.0f;
    #pragma unroll
    for (int k = 0; k < T_MAX; ++k) sum += s_e[k];
    const float inv = 1.0f / sum;

    // ---- chunk-0 extras: probs row + mtl segment-sum row ----
    if (chunk == 0) {
        if (tid < T_MAX) {
            const int pad = T_MAX - n;
            probs_out[sidx * T_MAX + tid] =
                (tid >= pad) ? s_e[tid - pad] * inv : 0.0f;
        }
        for (int i = tid; i < h4; i += 256) {
            f4 acc = {0.f, 0.f, 0.f, 0.f};
            for (int k = 0; k < n; ++k) {
                const float wk = s_e[k] * inv;
                const int r = min(o + k, rows - 1);
                acc += wk * mtl4[(size_t)r * h4 + i];
            }
            out_mtl[(size_t)sidx * h4 + i] = acc;
        }
    }

    // ---- main streaming body ----
    const int base = chunk * 1024 + tid;
    f4* outp = out_bert + (size_t)sidx * bert_cols4;

    if (n == 4) {
        const float w0 = s_e[0] * inv, w1 = s_e[1] * inv;
        const float w2 = s_e[2] * inv, w3 = s_e[3] * inv;
        const f4* r0 = bert + (size_t)min(o + 0, rows - 1) * bert_cols4;
        const f4* r1 = bert + (size_t)min(o + 1, rows - 1) * bert_cols4;
        const f4* r2 = bert + (size_t)min(o + 2, rows - 1) * bert_cols4;
        const f4* r3 = bert + (size_t)min(o + 3, rows - 1) * bert_cols4;

        f4 v[4][4];
        #pragma unroll
        for (int j = 0; j < 4; ++j) {
            const int i = base + j * 256;
            v[j][0] = __builtin_nontemporal_load(&r0[i]);
            v[j][1] = __builtin_nontemporal_load(&r1[i]);
            v[j][2] = __builtin_nontemporal_load(&r2[i]);
            v[j][3] = __builtin_nontemporal_load(&r3[i]);
        }
        #pragma unroll
        for (int j = 0; j < 4; ++j) {
            const int i = base + j * 256;
            f4 acc = w0 * v[j][0] + w1 * v[j][1] + w2 * v[j][2] + w3 * v[j][3];
            __builtin_nontemporal_store(acc, &outp[i]);
        }
    } else if (n == 1) {
        const float w0 = s_e[0] * inv;
        const f4* r0 = bert + (size_t)min(o, rows - 1) * bert_cols4;
        #pragma unroll
        for (int j = 0; j < 4; ++j) {
            const int i = base + j * 256;
            const f4 acc = w0 * __builtin_nontemporal_load(&r0[i]);
            __builtin_nontemporal_store(acc, &outp[i]);
        }
    } else {
        #pragma unroll
        for (int j = 0; j < 4; ++j) {
            const int i = base + j * 256;
            f4 acc = {0.f, 0.f, 0.f, 0.f};
            for (int k = 0; k < n; ++k) {
                const float wk = s_e[min(k, T_MAX - 1)] * inv;
                const int r = min(o + k, rows - 1);
                acc += wk * __builtin_nontemporal_load(&bert[(size_t)r * bert_cols4 + i]);
            }
            __builtin_nontemporal_store(acc, &outp[i]);
        }
    }
}

extern "C" void kernel_launch(void* const* d_in, const int* in_sizes, int n_in,
                              void* d_out, int out_size, void* d_ws, size_t ws_size,
                              hipStream_t stream) {
    const float* bert = (const float*)d_in[0];
    const float* hist = (const float*)d_in[1];
    const float* mtl  = (const float*)d_in[2];
    const float* W    = (const float*)d_in[3];
    const float* b    = (const float*)d_in[4];
    const int* slice_mask = (const int*)d_in[5];

    const int hidden = in_sizes[3];                       // 768
    const int rows   = in_sizes[1] / hidden;              // 64
    const int seq    = in_sizes[0] / (rows * hidden);     // 512
    const int S = out_size / (seq * hidden + hidden + T_MAX);   // 16

    float* out       = (float*)d_out;
    float* out_bert  = out;
    float* out_mtl   = out_bert + (size_t)S * seq * hidden;
    float* out_probs = out_mtl  + (size_t)S * hidden;

    const int bert_cols4 = seq * hidden / 4;              // 98304 (96*1024)
    const int chunk_f4   = 1024;                          // 4 f4 per thread
    const int nchunks    = (bert_cols4 + chunk_f4 - 1) / chunk_f4;  // 96
    const int grid       = S * nchunks;                   // 1536

    k_fused<<<grid, 256, 0, stream>>>((const f4*)bert, hist, (const f4*)mtl,
                                      W, b, slice_mask,
                                      S, rows, hidden,
                                      nchunks, bert_cols4,
                                      (f4*)out_bert, (f4*)out_mtl, out_probs);
}

// Round 9
// 156.226 us; speedup vs baseline: 1.0773x; 1.0024x over previous
//
#include <hip/hip_runtime.h>
#include <math.h>

#define T_MAX 11  // MAX_TURNS from the reference

typedef float f4 __attribute__((ext_vector_type(4)));  // nontemporal-compatible

// ---------------------------------------------------------------------------
// Single fused kernel. Grid = S * nchunks blocks of 256 (4 waves).
// Prologue per block (proven non-critical R6): slice_mask -> (o,n) in regs,
// one wave per row 768-dot, ONE barrier, per-thread softmax weights.
// Main body: 8 f4 columns per thread, n==4 fast path issues all 32
// independent NT loads (32 KB/wave in flight) before the FMAs; NT stores.
// chunk==0 blocks also write probs[sidx] and the mtl output row.
// ---------------------------------------------------------------------------
__global__ __launch_bounds__(256) void k_fused(
    const f4*    __restrict__ bert,        // [rows, bert_cols4]
    const float* __restrict__ hist,        // [rows, hidden]
    const f4*    __restrict__ mtl4,        // [rows, hidden/4]
    const float* __restrict__ W,           // [hidden]
    const float* __restrict__ b,           // [1]
    const int*   __restrict__ slice_mask,  // [>=S]
    int S, int rows, int hidden,
    int nchunks, int bert_cols4,
    f4*    __restrict__ out_bert,          // [S, bert_cols4]
    f4*    __restrict__ out_mtl,           // [S, hidden/4]
    float* __restrict__ probs_out)         // [S, T_MAX]
{
    __shared__ float s_e[T_MAX + 1];

    const int sidx  = blockIdx.x / nchunks;
    const int chunk = blockIdx.x - sidx * nchunks;
    const int tid   = threadIdx.x;
    const int lane  = tid & 63;
    const int wave  = tid >> 6;

    // ---- (o, n) in registers: uniform broadcast loads, no barrier ----
    int o = 0, n = 0;
    #pragma unroll
    for (int i = 0; i < 16; ++i) {          // S == 16 here
        const int v = (i < S) ? slice_mask[i] : 0;
        if (i < sidx)  o += v;
        if (i == sidx) n = v;
    }

    // ---- zero exp slots >= n (disjoint from wave writes below) ----
    if (tid < T_MAX && tid >= n) s_e[tid] = 0.0f;

    // ---- one wave per valid row dot-product ----
    const int h4 = hidden >> 2;             // 192
    const f4* W4 = (const f4*)W;
    for (int k = wave; k < n; k += 4) {
        const int idx = min(o + k, rows - 1);
        const f4* hrow = (const f4*)(hist + (size_t)idx * hidden);
        float acc = 0.0f;
        for (int j = lane; j < h4; j += 64) {
            const f4 hv = hrow[j];
            const f4 wv = W4[j];
            acc += hv.x * wv.x + hv.y * wv.y + hv.z * wv.z + hv.w * wv.w;
        }
        #pragma unroll
        for (int d = 32; d > 0; d >>= 1)
            acc += __shfl_down(acc, d);
        if (lane == 0) s_e[k] = expf(acc + b[0]);
    }
    __syncthreads();

    // ---- every thread: softmax denominator ----
    float sum = 0.0f;
    #pragma unroll
    for (int k = 0; k < T_MAX; ++k) sum += s_e[k];
    const float inv = 1.0f / sum;

    // ---- chunk-0 extras: probs row + mtl segment-sum row ----
    if (chunk == 0) {
        if (tid < T_MAX) {
            const int pad = T_MAX - n;
            probs_out[sidx * T_MAX + tid] =
                (tid >= pad) ? s_e[tid - pad] * inv : 0.0f;
        }
        for (int i = tid; i < h4; i += 256) {
            f4 acc = {0.f, 0.f, 0.f, 0.f};
            for (int k = 0; k < n; ++k) {
                const float wk = s_e[k] * inv;
                const int r = min(o + k, rows - 1);
                acc += wk * mtl4[(size_t)r * h4 + i];
            }
            out_mtl[(size_t)sidx * h4 + i] = acc;
        }
    }

    // ---- main streaming body: 8 f4 columns per thread ----
    const int base = chunk * 2048 + tid;
    f4* outp = out_bert + (size_t)sidx * bert_cols4;

    if (n == 4) {
        const float w0 = s_e[0] * inv, w1 = s_e[1] * inv;
        const float w2 = s_e[2] * inv, w3 = s_e[3] * inv;
        const f4* r0 = bert + (size_t)min(o + 0, rows - 1) * bert_cols4;
        const f4* r1 = bert + (size_t)min(o + 1, rows - 1) * bert_cols4;
        const f4* r2 = bert + (size_t)min(o + 2, rows - 1) * bert_cols4;
        const f4* r3 = bert + (size_t)min(o + 3, rows - 1) * bert_cols4;

        f4 v[8][4];
        #pragma unroll
        for (int j = 0; j < 8; ++j) {
            const int i = base + j * 256;
            v[j][0] = __builtin_nontemporal_load(&r0[i]);
            v[j][1] = __builtin_nontemporal_load(&r1[i]);
            v[j][2] = __builtin_nontemporal_load(&r2[i]);
            v[j][3] = __builtin_nontemporal_load(&r3[i]);
        }
        #pragma unroll
        for (int j = 0; j < 8; ++j) {
            const int i = base + j * 256;
            f4 acc = w0 * v[j][0] + w1 * v[j][1] + w2 * v[j][2] + w3 * v[j][3];
            __builtin_nontemporal_store(acc, &outp[i]);
        }
    } else if (n == 1) {
        const float w0 = s_e[0] * inv;
        const f4* r0 = bert + (size_t)min(o, rows - 1) * bert_cols4;
        f4 v[8];
        #pragma unroll
        for (int j = 0; j < 8; ++j)
            v[j] = __builtin_nontemporal_load(&r0[base + j * 256]);
        #pragma unroll
        for (int j = 0; j < 8; ++j) {
            const f4 acc = w0 * v[j];
            __builtin_nontemporal_store(acc, &outp[base + j * 256]);
        }
    } else {
        #pragma unroll
        for (int j = 0; j < 8; ++j) {
            const int i = base + j * 256;
            f4 acc = {0.f, 0.f, 0.f, 0.f};
            for (int k = 0; k < n; ++k) {
                const float wk = s_e[min(k, T_MAX - 1)] * inv;
                const int r = min(o + k, rows - 1);
                acc += wk * __builtin_nontemporal_load(&bert[(size_t)r * bert_cols4 + i]);
            }
            __builtin_nontemporal_store(acc, &outp[i]);
        }
    }
}

extern "C" void kernel_launch(void* const* d_in, const int* in_sizes, int n_in,
                              void* d_out, int out_size, void* d_ws, size_t ws_size,
                              hipStream_t stream) {
    const float* bert = (const float*)d_in[0];
    const float* hist = (const float*)d_in[1];
    const float* mtl  = (const float*)d_in[2];
    const float* W    = (const float*)d_in[3];
    const float* b    = (const float*)d_in[4];
    const int* slice_mask = (const int*)d_in[5];

    const int hidden = in_sizes[3];                       // 768
    const int rows   = in_sizes[1] / hidden;              // 64
    const int seq    = in_sizes[0] / (rows * hidden);     // 512
    const int S = out_size / (seq * hidden + hidden + T_MAX);   // 16

    float* out       = (float*)d_out;
    float* out_bert  = out;
    float* out_mtl   = out_bert + (size_t)S * seq * hidden;
    float* out_probs = out_mtl  + (size_t)S * hidden;

    const int bert_cols4 = seq * hidden / 4;              // 98304 (48*2048)
    const int chunk_f4   = 2048;                          // 8 f4 per thread
    const int nchunks    = (bert_cols4 + chunk_f4 - 1) / chunk_f4;  // 48
    const int grid       = S * nchunks;                   // 768

    k_fused<<<grid, 256, 0, stream>>>((const f4*)bert, hist, (const f4*)mtl,
                                      W, b, slice_mask,
                                      S, rows, hidden,
                                      nchunks, bert_cols4,
                                      (f4*)out_bert, (f4*)out_mtl, out_probs);
}